// Round 1
// baseline (1071.528 us; speedup 1.0000x reference)
//
#include <hip/hip_runtime.h>
#include <math.h>

#define BATCH 8
#define H 256
#define W 256
#define HW (H*W)
#define TS 32
#define KS 9
#define ITER_N 100

struct GaussW { float g[KS]; };

__device__ __forceinline__ int refl(int i, int n) {
    // jnp.pad mode='reflect': mirror without repeating the edge
    if (i < 0) i = -i;
    if (i >= n) i = 2*n - 2 - i;
    return i;
}

__global__ void luma_kernel(const float* __restrict__ x, float* __restrict__ u0) {
    int idx = blockIdx.x * blockDim.x + threadIdx.x;
    if (idx >= BATCH*HW) return;
    int b = idx / HW;
    int rem = idx - b*HW;
    const float* xb = x + (size_t)b*3*HW + rem;
    u0[idx] = 0.299f*xb[0] + 0.587f*xb[HW] + 0.114f*xb[2*HW];
}

// vertical 9-tap blur with reflect rows (for gauss_rho precompute)
__global__ void vblur_kernel(const float* __restrict__ in, float* __restrict__ out, GaussW gw) {
    int idx = blockIdx.x * blockDim.x + threadIdx.x;
    if (idx >= BATCH*HW) return;
    int b = idx >> 16;
    int y = (idx >> 8) & 255;
    int xx = idx & 255;
    const float* ib = in + b*HW;
    float acc = 0.f;
#pragma unroll
    for (int t = 0; t < KS; ++t)
        acc += gw.g[t] * ib[refl(y - 4 + t, H)*W + xx];
    out[idx] = acc;
}

// horizontal 9-tap blur with reflect cols (for gauss_rho precompute)
__global__ void hblur_kernel(const float* __restrict__ in, float* __restrict__ out, GaussW gw) {
    int idx = blockIdx.x * blockDim.x + threadIdx.x;
    if (idx >= BATCH*HW) return;
    int b = idx >> 16;
    int y = (idx >> 8) & 255;
    int xx = idx & 255;
    const float* ib = in + b*HW + y*W;
    float acc = 0.f;
#pragma unroll
    for (int t = 0; t < KS; ++t)
        acc += gw.g[t] * ib[refl(xx - 4 + t, W)];
    out[idx] = acc;
}

// One diffusion iteration, fully fused per 32x32 tile.
// Needs u in an 11x11 neighborhood: halo 5 (Sobel r=1 with ZERO pad, then 9-tap
// blur r=4 of the products with REFLECT pad of the product image).
__global__ void __launch_bounds__(256) step_kernel(
        const float* __restrict__ uin, float* __restrict__ uout,
        const float* __restrict__ rho,
        const float* __restrict__ dtp, const float* __restrict__ kp,
        GaussW gw)
{
    __shared__ float su[42][44];                     // u tile + halo 5 (zero outside image)
    __shared__ float p11[40][42], p12[40][42], p22[40][42]; // products on [-4,36)^2 (reflect-mapped)
    __shared__ float v11[32][42], v12[32][42], v22[32][42]; // vertical blur: rows [0,32), cols [-4,36)

    const int tid = threadIdx.x;
    const int tx0 = blockIdx.x * TS, ty0 = blockIdx.y * TS, b = blockIdx.z;
    const float* ub = uin + b*HW;

    // Phase 1: load u tile + halo (zero pad outside image -> Sobel SAME semantics)
    for (int i = tid; i < 42*42; i += 256) {
        int ly = i / 42, lx = i - ly*42;
        int gy = ty0 - 5 + ly, gx = tx0 - 5 + lx;
        float v = 0.f;
        if (gy >= 0 && gy < H && gx >= 0 && gx < W) v = ub[gy*W + gx];
        su[ly][lx] = v;
    }
    __syncthreads();

    // Phase 2: Sobel + structure-tensor products at reflect-mapped coords
    for (int i = tid; i < 40*40; i += 256) {
        int py = i / 40, px = i - py*40;
        int ry = refl(ty0 - 4 + py, H), rx = refl(tx0 - 4 + px, W);
        int sy = ry - ty0 + 5, sx = rx - tx0 + 5;
        float a  = su[sy-1][sx-1], b0 = su[sy-1][sx], c0 = su[sy-1][sx+1];
        float d0 = su[sy  ][sx-1],                    e0 = su[sy  ][sx+1];
        float f0 = su[sy+1][sx-1], g0 = su[sy+1][sx], h0 = su[sy+1][sx+1];
        float gxv = (c0 - a) + 2.f*(e0 - d0) + (h0 - f0);
        float gyv = (f0 - a) + 2.f*(g0 - b0) + (h0 - c0);
        p11[py][px] = gxv*gxv;
        p12[py][px] = gxv*gyv;
        p22[py][px] = gyv*gyv;
    }
    __syncthreads();

    // Phase 3: vertical 9-tap blur of the three product planes
    for (int i = tid; i < 32*40; i += 256) {
        int r = i / 40, px = i - r*40;
        float a11 = 0.f, a12 = 0.f, a22 = 0.f;
#pragma unroll
        for (int t = 0; t < KS; ++t) {
            float w = gw.g[t];
            a11 += w * p11[r+t][px];
            a12 += w * p12[r+t][px];
            a22 += w * p22[r+t][px];
        }
        v11[r][px] = a11; v12[r][px] = a12; v22[r][px] = a22;
    }
    __syncthreads();

    // Phase 4: horizontal blur + eigenvalues + diffusion update
    const float dt = *dtp;
    const float kk = *kp;
    const float k2 = kk * kk;

    for (int i = tid; i < 32*32; i += 256) {
        int r = i >> 5, c = i & 31;
        float s11 = 0.f, s12 = 0.f, s22 = 0.f;
#pragma unroll
        for (int t = 0; t < KS; ++t) {
            float w = gw.g[t];
            s11 += w * v11[r][c+t];
            s12 += w * v12[r][c+t];
            s22 += w * v22[r][c+t];
        }
        int gidx = b*HW + (ty0 + r)*W + (tx0 + c);
        float rv = rho[gidx];
        s11 -= rv; s12 -= rv; s22 -= rv;
        float df = s11 - s22;
        float tm = sqrtf(df*df + 4.f*s12*s12);
        float sm = s11 + s22;
        float lam1 = 0.5f*(sm + tm);
        float lam2 = 0.5f*(sm - tm);
        float c1 = expf(-(lam1*lam1)/k2);
        float c2 = expf(-(lam2*lam2)/k2);
        uout[gidx] = su[r+5][c+5] + dt*(c1*lam1 + c2*lam2);
    }
}

__global__ void expand_kernel(const float* __restrict__ u, float* __restrict__ out) {
    int idx = blockIdx.x * blockDim.x + threadIdx.x;
    if (idx >= BATCH*HW) return;
    int b = idx / HW;
    int rem = idx - b*HW;
    float v = u[idx];
    float* ob = out + (size_t)b*3*HW + rem;
    ob[0] = v; ob[HW] = v; ob[2*HW] = v;
}

extern "C" void kernel_launch(void* const* d_in, const int* in_sizes, int n_in,
                              void* d_out, int out_size, void* d_ws, size_t ws_size,
                              hipStream_t stream) {
    const float* x   = (const float*)d_in[0];
    const float* dtp = (const float*)d_in[1];
    const float* kp  = (const float*)d_in[2];
    float* out = (float*)d_out;

    float* u_a = (float*)d_ws;
    float* u_b = u_a + BATCH*HW;
    float* rho = u_b + BATCH*HW;

    GaussW gw;
    {
        double s = 0.0, wd[KS];
        for (int i = 0; i < KS; ++i) {
            double xd = (double)i - 4.0;
            wd[i] = exp(-0.5 * (xd/4.0) * (xd/4.0));
            s += wd[i];
        }
        for (int i = 0; i < KS; ++i) gw.g[i] = (float)(wd[i] / s);
    }

    dim3 b1(256), g1((BATCH*HW + 255)/256);
    luma_kernel<<<g1, b1, 0, stream>>>(x, u_a);
    // gauss_rho = separable reflect-blur of u0; u_b doubles as tmp
    vblur_kernel<<<g1, b1, 0, stream>>>(u_a, u_b, gw);
    hblur_kernel<<<g1, b1, 0, stream>>>(u_b, rho, gw);

    dim3 gs(W/TS, H/TS, BATCH), bs(256);
    float* cur = u_a;
    float* nxt = u_b;
    for (int it = 0; it < ITER_N; ++it) {
        step_kernel<<<gs, bs, 0, stream>>>(cur, nxt, rho, dtp, kp, gw);
        float* t = cur; cur = nxt; nxt = t;
    }
    expand_kernel<<<g1, b1, 0, stream>>>(cur, out);
}